// Round 2
// baseline (1256.254 us; speedup 1.0000x reference)
//
#include <hip/hip_runtime.h>
#include <math.h>

#define NHEAD 8
#define DK 32
#define DIN 512
#define BB 16
#define TT 1024
#define DH 64                      // DIN / NHEAD
#define EE 256                     // NHEAD * DK
#define OUT_OFF (NHEAD*BB*TT*DH)   // 8388608 floats, then attn
#define INVTEMP 0.17677669529663687f  // 1/sqrt(32)

// ---------------------------------------------------------------------------
// Kernel 0: mask normalize.  pad_mask may arrive as int32 (harness "integer ->
// const int*") or as raw 1-byte bools. Detect at runtime: in int32 layout the
// bytes at offsets 4i+{1,2,3} are all zero (values are 0/1); in byte layout
// those positions are real bool values (~50% ones over 16K elements).
// Writes a normalized 1-byte mask into d_ws. One block, ~2us.
// ---------------------------------------------------------------------------
__global__ __launch_bounds__(256)
void mask_repack_kernel(const unsigned char* __restrict__ raw,
                        unsigned char* __restrict__ norm)
{
    __shared__ int sflag;
    const int t = threadIdx.x;
    if (t == 0) sflag = 0;
    __syncthreads();

    int f = 0;
    // scan first 16384 bytes (safe under both layouts: byte layout is exactly
    // 16384 bytes; int layout is 65536)
    for (int i = t; i < BB*TT/4; i += 256) {
        uchar4 b4 = reinterpret_cast<const uchar4*>(raw)[i];
        f |= (int)b4.y | (int)b4.z | (int)b4.w;
    }
    if (f) atomicOr(&sflag, 1);
    __syncthreads();

    if (sflag) {                           // byte layout
        for (int i = t; i < BB*TT; i += 256)
            norm[i] = raw[i] ? 1 : 0;
    } else {                               // int32 layout
        const int* ri = reinterpret_cast<const int*>(raw);
        for (int i = t; i < BB*TT; i += 256)
            norm[i] = ri[i] ? 1 : 0;
    }
}

// ---------------------------------------------------------------------------
// Kernel 1: projection GEMM.  C[m][e] = sum_d v[m][d]*W[e][d] + bias[e]
// M = BB*TT = 16384, N = 512 (256 q-cols then 256 k-cols), K = 512.
// Tiles 128x128, BK=16, 256 threads, 8x8 micro-tile.
// qh is additionally scaled by 1/sqrt(DK) so the score kernel skips the divide.
// ---------------------------------------------------------------------------
__global__ __launch_bounds__(256)
void proj_kernel(const float* __restrict__ v,
                 const float* __restrict__ Wq, const float* __restrict__ bq,
                 const float* __restrict__ Wk, const float* __restrict__ bk,
                 float* __restrict__ qh, float* __restrict__ kh)
{
    __shared__ float As[16][132];   // [kk][m], padded
    __shared__ float Bs[16][132];   // [kk][e], padded

    const int m0 = blockIdx.x * 128;
    const int nb = blockIdx.y;                 // 0,1 -> q ; 2,3 -> k
    const bool isQ = (nb < 2);
    const float* __restrict__ W    = isQ ? (Wq + (size_t)nb*128*DIN)
                                         : (Wk + (size_t)(nb-2)*128*DIN);
    const float* __restrict__ bias = isQ ? (bq + nb*128) : (bk + (nb-2)*128);
    float* __restrict__ C          = isQ ? qh : kh;
    const int   c0    = (nb & 1) * 128;
    const float scale = isQ ? INVTEMP : 1.0f;

    const int t  = threadIdx.x;
    const int tx = t & 15, ty = t >> 4;

    float acc[8][8];
    #pragma unroll
    for (int i = 0; i < 8; ++i)
        #pragma unroll
        for (int j = 0; j < 8; ++j) acc[i][j] = 0.0f;

    for (int k0 = 0; k0 < DIN; k0 += 16) {
        #pragma unroll
        for (int l = 0; l < 2; ++l) {          // 512 float4 per tile, 2 per thread
            int idx = t + l*256;
            int row = idx >> 2, c4 = idx & 3;
            float4 a = *reinterpret_cast<const float4*>(
                &v[(size_t)(m0+row)*DIN + k0 + c4*4]);
            As[c4*4+0][row] = a.x; As[c4*4+1][row] = a.y;
            As[c4*4+2][row] = a.z; As[c4*4+3][row] = a.w;
            float4 b = *reinterpret_cast<const float4*>(
                &W[(size_t)row*DIN + k0 + c4*4]);
            Bs[c4*4+0][row] = b.x; Bs[c4*4+1][row] = b.y;
            Bs[c4*4+2][row] = b.z; Bs[c4*4+3][row] = b.w;
        }
        __syncthreads();
        #pragma unroll
        for (int kk = 0; kk < 16; ++kk) {
            float a[8], b[8];
            *reinterpret_cast<float4*>(&a[0]) = *reinterpret_cast<const float4*>(&As[kk][ty*8]);
            *reinterpret_cast<float4*>(&a[4]) = *reinterpret_cast<const float4*>(&As[kk][ty*8+4]);
            *reinterpret_cast<float4*>(&b[0]) = *reinterpret_cast<const float4*>(&Bs[kk][tx*8]);
            *reinterpret_cast<float4*>(&b[4]) = *reinterpret_cast<const float4*>(&Bs[kk][tx*8+4]);
            #pragma unroll
            for (int i = 0; i < 8; ++i)
                #pragma unroll
                for (int j = 0; j < 8; ++j)
                    acc[i][j] += a[i]*b[j];
        }
        __syncthreads();
    }

    #pragma unroll
    for (int i = 0; i < 8; ++i) {
        float4 o0, o1;
        o0.x = (acc[i][0] + bias[tx*8+0]) * scale;
        o0.y = (acc[i][1] + bias[tx*8+1]) * scale;
        o0.z = (acc[i][2] + bias[tx*8+2]) * scale;
        o0.w = (acc[i][3] + bias[tx*8+3]) * scale;
        o1.x = (acc[i][4] + bias[tx*8+4]) * scale;
        o1.y = (acc[i][5] + bias[tx*8+5]) * scale;
        o1.z = (acc[i][6] + bias[tx*8+6]) * scale;
        o1.w = (acc[i][7] + bias[tx*8+7]) * scale;
        size_t base = (size_t)(m0 + ty*8 + i)*EE + c0 + tx*8;
        *reinterpret_cast<float4*>(&C[base])   = o0;
        *reinterpret_cast<float4*>(&C[base+4]) = o1;
    }
}

// ---------------------------------------------------------------------------
// Kernel 2: fused scores + softmax + attn-write + PV.
// Block = 256 threads = 4 waves, handles (b, h, 16 q-rows).
// Wave w owns q-rows 4w..4w+3; lane holds scores for k = c*128 + 2*lane + {0,1}
// (full row of 1024 scores kept in registers: 4 rows x 16 regs).
// ---------------------------------------------------------------------------
#define PVSTEP(PC, VV)                                                                          \
    acc[0][0] += p0.PC*VV.x; acc[0][1] += p0.PC*VV.y; acc[0][2] += p0.PC*VV.z; acc[0][3] += p0.PC*VV.w; \
    acc[1][0] += p1.PC*VV.x; acc[1][1] += p1.PC*VV.y; acc[1][2] += p1.PC*VV.z; acc[1][3] += p1.PC*VV.w; \
    acc[2][0] += p2.PC*VV.x; acc[2][1] += p2.PC*VV.y; acc[2][2] += p2.PC*VV.z; acc[2][3] += p2.PC*VV.w; \
    acc[3][0] += p3.PC*VV.x; acc[3][1] += p3.PC*VV.y; acc[3][2] += p3.PC*VV.z; acc[3][3] += p3.PC*VV.w;

__global__ __launch_bounds__(256)
void attn_kernel(const float* __restrict__ qh, const float* __restrict__ kh,
                 const float* __restrict__ v, const unsigned char* __restrict__ mask,
                 float* __restrict__ out)
{
    __shared__ float qhs[16][32];     // q fragments for this block
    __shared__ float khsT[32][134];   // k chunk, transposed [d][k], pad -> 2-way max
    __shared__ float vhs[128][64];    // v chunk [k][d]
    __shared__ float pbuf[16][132];   // p chunk [row][k]
    __shared__ float obuf[4][16][64]; // per-wave partial outputs

    const int q0   = blockIdx.x * 16;
    const int b    = blockIdx.y;
    const int h    = blockIdx.z;
    const int t    = threadIdx.x;
    const int lane = t & 63, w = t >> 6;
    const int k0l  = 2*lane;

    #pragma unroll
    for (int l = 0; l < 2; ++l) {
        int idx = t + l*256;
        int r = idx >> 5, d = idx & 31;
        qhs[r][d] = qh[(size_t)(b*TT + q0 + r)*EE + h*DK + d];
    }
    __syncthreads();

    const float* __restrict__ khb = kh + (size_t)b*TT*EE + h*DK;

    float s[4][16];                   // scores -> p (compile-time indexed only)

    #pragma unroll
    for (int c = 0; c < 8; ++c) {     // k chunks of 128
        #pragma unroll
        for (int l = 0; l < 16; ++l) {   // stage khsT (transpose)
            int idx = t + 256*l;
            int d = idx & 31, k = idx >> 5;
            khsT[d][k] = khb[(size_t)(c*128 + k)*EE + d];
        }
        __syncthreads();

        float s0[4] = {0,0,0,0}, s1[4] = {0,0,0,0};
        #pragma unroll
        for (int dg = 0; dg < 8; ++dg) {
            float2 ka = *reinterpret_cast<const float2*>(&khsT[dg*4+0][k0l]);
            float2 kb = *reinterpret_cast<const float2*>(&khsT[dg*4+1][k0l]);
            float2 kc = *reinterpret_cast<const float2*>(&khsT[dg*4+2][k0l]);
            float2 kd = *reinterpret_cast<const float2*>(&khsT[dg*4+3][k0l]);
            #pragma unroll
            for (int rr = 0; rr < 4; ++rr) {
                float4 q4 = *reinterpret_cast<const float4*>(&qhs[4*w+rr][dg*4]);
                s0[rr] += q4.x*ka.x + q4.y*kb.x + q4.z*kc.x + q4.w*kd.x;
                s1[rr] += q4.x*ka.y + q4.y*kb.y + q4.z*kc.y + q4.w*kd.y;
            }
        }
        // qh was pre-scaled by 1/sqrt(dk); mask AFTER scaling, exact -1000.
        uchar2 mk = *reinterpret_cast<const uchar2*>(&mask[(size_t)b*TT + c*128 + k0l]);
        #pragma unroll
        for (int rr = 0; rr < 4; ++rr) {
            s[rr][2*c+0] = mk.x ? -1000.0f : s0[rr];
            s[rr][2*c+1] = mk.y ? -1000.0f : s1[rr];
        }
        __syncthreads();
    }

    // ---- softmax over 1024 k (16 regs/lane + 64-lane butterfly) ----
    #pragma unroll
    for (int rr = 0; rr < 4; ++rr) {
        float m = s[rr][0];
        #pragma unroll
        for (int j = 1; j < 16; ++j) m = fmaxf(m, s[rr][j]);
        #pragma unroll
        for (int o = 32; o >= 1; o >>= 1) m = fmaxf(m, __shfl_xor(m, o, 64));
        float l = 0.0f;
        #pragma unroll
        for (int j = 0; j < 16; ++j) { float e = __expf(s[rr][j] - m); s[rr][j] = e; l += e; }
        #pragma unroll
        for (int o = 32; o >= 1; o >>= 1) l += __shfl_xor(l, o, 64);
        float inv = 1.0f / l;
        #pragma unroll
        for (int j = 0; j < 16; ++j) s[rr][j] *= inv;
    }

    // ---- write attn matrix (coalesced: lanes cover consecutive k) ----
    float* __restrict__ attnout = out + OUT_OFF + (size_t)((h*BB + b)*TT + q0)*TT;
    #pragma unroll
    for (int rr = 0; rr < 4; ++rr) {
        float* __restrict__ rowp = attnout + (size_t)(4*w+rr)*TT;
        #pragma unroll
        for (int c = 0; c < 8; ++c) {
            *reinterpret_cast<float2*>(&rowp[c*128 + k0l]) =
                make_float2(s[rr][2*c], s[rr][2*c+1]);
        }
    }

    // ---- PV: out[q][d] = sum_k p[q][k] * vh[k][d] ----
    float acc[4][4];
    #pragma unroll
    for (int i = 0; i < 4; ++i)
        #pragma unroll
        for (int j = 0; j < 4; ++j) acc[i][j] = 0.0f;

    const float* __restrict__ vb = v + (size_t)b*TT*DIN + h*DH;
    const int rg = lane >> 4, dg = lane & 15;   // lane -> (4 rows, 4 d's)

    #pragma unroll
    for (int vc = 0; vc < 8; ++vc) {
        __syncthreads();                        // previous chunk fully consumed
        #pragma unroll
        for (int l = 0; l < 8; ++l) {           // stage vhs: 128 x 64
            int idx = t + 256*l;
            int row = idx >> 4, c4 = idx & 15;
            *reinterpret_cast<float4*>(&vhs[row][c4*4]) =
                *reinterpret_cast<const float4*>(&vb[(size_t)(vc*128+row)*DIN + c4*4]);
        }
        #pragma unroll
        for (int rr = 0; rr < 4; ++rr) {        // stage p chunk [16][128]
            *reinterpret_cast<float2*>(&pbuf[4*w+rr][k0l]) =
                make_float2(s[rr][2*vc], s[rr][2*vc+1]);
        }
        __syncthreads();

        // wave w covers k-subrange [w*32, w*32+32) of this chunk
        #pragma unroll
        for (int kk = 0; kk < 32; kk += 4) {
            const int kbase = w*32 + kk;
            float4 p0 = *reinterpret_cast<const float4*>(&pbuf[rg*4+0][kbase]);
            float4 p1 = *reinterpret_cast<const float4*>(&pbuf[rg*4+1][kbase]);
            float4 p2 = *reinterpret_cast<const float4*>(&pbuf[rg*4+2][kbase]);
            float4 p3 = *reinterpret_cast<const float4*>(&pbuf[rg*4+3][kbase]);
            { float4 vv = *reinterpret_cast<const float4*>(&vhs[kbase+0][dg*4]); PVSTEP(x, vv) }
            { float4 vv = *reinterpret_cast<const float4*>(&vhs[kbase+1][dg*4]); PVSTEP(y, vv) }
            { float4 vv = *reinterpret_cast<const float4*>(&vhs[kbase+2][dg*4]); PVSTEP(z, vv) }
            { float4 vv = *reinterpret_cast<const float4*>(&vhs[kbase+3][dg*4]); PVSTEP(w, vv) }
        }
    }

    // ---- cross-wave reduce of k-partials, coalesced store ----
    #pragma unroll
    for (int rr = 0; rr < 4; ++rr) {
        *reinterpret_cast<float4*>(&obuf[w][rg*4+rr][dg*4]) =
            make_float4(acc[rr][0], acc[rr][1], acc[rr][2], acc[rr][3]);
    }
    __syncthreads();
    {
        int r = t >> 4, c4 = t & 15;
        float4 r0 = *reinterpret_cast<const float4*>(&obuf[0][r][c4*4]);
        float4 r1 = *reinterpret_cast<const float4*>(&obuf[1][r][c4*4]);
        float4 r2 = *reinterpret_cast<const float4*>(&obuf[2][r][c4*4]);
        float4 r3 = *reinterpret_cast<const float4*>(&obuf[3][r][c4*4]);
        float4 o;
        o.x = r0.x + r1.x + r2.x + r3.x;
        o.y = r0.y + r1.y + r2.y + r3.y;
        o.z = r0.z + r1.z + r2.z + r3.z;
        o.w = r0.w + r1.w + r2.w + r3.w;
        *reinterpret_cast<float4*>(
            &out[(size_t)((h*BB + b)*TT + q0 + r)*DH + c4*4]) = o;
    }
}

// ---------------------------------------------------------------------------
extern "C" void kernel_launch(void* const* d_in, const int* in_sizes, int n_in,
                              void* d_out, int out_size, void* d_ws, size_t ws_size,
                              hipStream_t stream)
{
    // setup_inputs order: q, k, v, pad_mask, W_q, b_q, W_k, b_k
    const float* v  = (const float*)d_in[2];
    const unsigned char* mask_raw = (const unsigned char*)d_in[3];
    const float* Wq = (const float*)d_in[4];
    const float* bq = (const float*)d_in[5];
    const float* Wk = (const float*)d_in[6];
    const float* bk = (const float*)d_in[7];
    float* out = (float*)d_out;

    float* qh = (float*)d_ws;                       // 16384 x 256 f32 (16.8 MB)
    float* kh = qh + (size_t)BB*TT*EE;              // 16384 x 256 f32 (16.8 MB)
    unsigned char* mask_norm =
        (unsigned char*)(kh + (size_t)BB*TT*EE);    // 16384 bytes

    mask_repack_kernel<<<1, 256, 0, stream>>>(mask_raw, mask_norm);

    dim3 pgrid(128, 4);
    proj_kernel<<<pgrid, 256, 0, stream>>>(v, Wq, bq, Wk, bk, qh, kh);

    dim3 agrid(TT/16, BB, NHEAD);
    attn_kernel<<<agrid, 256, 0, stream>>>(qh, kh, v, mask_norm, out);
}

// Round 3
// 1037.409 us; speedup vs baseline: 1.2110x; 1.2110x over previous
//
#include <hip/hip_runtime.h>
#include <math.h>

#define NHEAD 8
#define DK 32
#define DIN 512
#define BB 16
#define TT 1024
#define DH 64
#define EE 256
#define OUT_OFF ((size_t)NHEAD*BB*TT*DH)
#define INVTEMP 0.17677669529663687f  // 1/sqrt(32)

typedef short bf16x8 __attribute__((ext_vector_type(8)));
typedef float f32x4  __attribute__((ext_vector_type(4)));

__device__ __forceinline__ short f2bf(float f) {
    union { float f; unsigned u; } c; c.f = f;
    unsigned u = c.u;
    unsigned r = (u + 0x7fffu + ((u >> 16) & 1u)) >> 16;   // RNE
    return (short)r;
}
__device__ __forceinline__ float bf2f(short s) {
    union { unsigned u; float f; } c;
    c.u = ((unsigned)(unsigned short)s) << 16;
    return c.f;
}

// ---------------------------------------------------------------------------
// Kernel 0: mask normalize (layout-robust, proven in R2).
// ---------------------------------------------------------------------------
__global__ __launch_bounds__(256)
void mask_repack_kernel(const unsigned char* __restrict__ raw,
                        unsigned char* __restrict__ norm)
{
    __shared__ int sflag;
    const int t = threadIdx.x;
    if (t == 0) sflag = 0;
    __syncthreads();
    int f = 0;
    for (int i = t; i < BB*TT/4; i += 256) {
        uchar4 b4 = reinterpret_cast<const uchar4*>(raw)[i];
        f |= (int)b4.y | (int)b4.z | (int)b4.w;
    }
    if (f) atomicOr(&sflag, 1);
    __syncthreads();
    if (sflag) {
        for (int i = t; i < BB*TT; i += 256) norm[i] = raw[i] ? 1 : 0;
    } else {
        const int* ri = reinterpret_cast<const int*>(raw);
        for (int i = t; i < BB*TT; i += 256) norm[i] = ri[i] ? 1 : 0;
    }
}

// ---------------------------------------------------------------------------
// Kernel 1: W -> hi/lo bf16 (rows 0-255 = Wq * INVTEMP, 256-511 = Wk),
// bias vector bc[512] (q part pre-scaled).
// ---------------------------------------------------------------------------
__global__ __launch_bounds__(256)
void conv_w_kernel(const float* __restrict__ Wq, const float* __restrict__ bq,
                   const float* __restrict__ Wk, const float* __restrict__ bk,
                   short* __restrict__ Whi, short* __restrict__ Wlo,
                   float* __restrict__ bc)
{
    const int e = blockIdx.x;             // 0..511
    const float sc = (e < 256) ? INVTEMP : 1.0f;
    const float* src = (e < 256) ? (Wq + (size_t)e*DIN) : (Wk + (size_t)(e-256)*DIN);
    for (int d = threadIdx.x; d < DIN; d += 256) {
        float f = src[d] * sc;
        short h = f2bf(f);
        Whi[(size_t)e*DIN + d] = h;
        Wlo[(size_t)e*DIN + d] = f2bf(f - bf2f(h));
    }
    if (threadIdx.x == 0)
        bc[e] = ((e < 256) ? bq[e] : bk[e-256]) * sc;
}

// ---------------------------------------------------------------------------
// Kernel 2: v -> vT_hi[b][h][dh][t] bf16 (per-head transpose for PV B-frags).
// LDS 64x65 tile; both LDS phases conflict-free (stride 65).
// ---------------------------------------------------------------------------
__global__ __launch_bounds__(256)
void conv_vt_kernel(const float* __restrict__ v, short* __restrict__ vT)
{
    __shared__ float tile[64][65];
    const int t0 = blockIdx.x * 64;
    const int b = blockIdx.y, h = blockIdx.z;
    const int t = threadIdx.x;
    #pragma unroll
    for (int i = 0; i < 16; ++i) {
        int idx = i*256 + t;
        int r = idx >> 6, dd = idx & 63;
        tile[dd][r] = v[((size_t)b*TT + t0 + r)*DIN + h*DH + dd];
    }
    __syncthreads();
    const int d = t >> 2, seg = t & 3;
    bf16x8 o0, o1;
    #pragma unroll
    for (int j = 0; j < 8; ++j) {
        o0[j] = f2bf(tile[d][seg*16 + j]);
        o1[j] = f2bf(tile[d][seg*16 + 8 + j]);
    }
    short* dst = vT + ((size_t)(b*NHEAD + h)*DH + d)*TT + t0 + seg*16;
    *(bf16x8*)(dst)     = o0;
    *(bf16x8*)(dst + 8) = o1;
}

// ---------------------------------------------------------------------------
// Kernel 3: projection via split-bf16 MFMA (3-pass).
// C[m][e] = sum_d v[m][d] * W[e][d] + bias; M=16384, N=512, K=512.
// Block = 4 waves; wave = 16 m-rows x 64 e-cols; no LDS (W is L2-resident).
// v converted to hi/lo bf16 in registers on the fly.
// Epilogue writes P_hi/P_lo bf16 (qh pre-scaled via folded W/bias).
// ---------------------------------------------------------------------------
__global__ __launch_bounds__(256)
void proj_kernel(const float* __restrict__ v, const short* __restrict__ Whi,
                 const short* __restrict__ Wlo, const float* __restrict__ bc,
                 short* __restrict__ Phi, short* __restrict__ Plo)
{
    const int t = threadIdx.x;
    const int lane = t & 63, w = t >> 6;
    const int x = lane & 15, g = lane >> 4;
    const int m0 = blockIdx.x * 64 + w * 16;
    const int n0 = blockIdx.y * 64;

    const float* arow = v + (size_t)(m0 + x) * DIN;
    f32x4 acc[4];
    #pragma unroll
    for (int cc = 0; cc < 4; ++cc) {
        acc[cc][0] = 0.f; acc[cc][1] = 0.f; acc[cc][2] = 0.f; acc[cc][3] = 0.f;
    }

    for (int d0 = 0; d0 < DIN; d0 += 32) {
        float4 a0 = *(const float4*)(arow + d0 + g*8);
        float4 a1 = *(const float4*)(arow + d0 + g*8 + 4);
        float av[8] = {a0.x, a0.y, a0.z, a0.w, a1.x, a1.y, a1.z, a1.w};
        bf16x8 ahi, alo;
        #pragma unroll
        for (int j = 0; j < 8; ++j) {
            short hh = f2bf(av[j]);
            ahi[j] = hh;
            alo[j] = f2bf(av[j] - bf2f(hh));
        }
        #pragma unroll
        for (int cc = 0; cc < 4; ++cc) {
            size_t boff = (size_t)(n0 + cc*16 + x) * DIN + d0 + g*8;
            bf16x8 bhi = *(const bf16x8*)(Whi + boff);
            bf16x8 blo = *(const bf16x8*)(Wlo + boff);
            acc[cc] = __builtin_amdgcn_mfma_f32_16x16x32_bf16(ahi, bhi, acc[cc], 0, 0, 0);
            acc[cc] = __builtin_amdgcn_mfma_f32_16x16x32_bf16(alo, bhi, acc[cc], 0, 0, 0);
            acc[cc] = __builtin_amdgcn_mfma_f32_16x16x32_bf16(ahi, blo, acc[cc], 0, 0, 0);
        }
    }

    #pragma unroll
    for (int cc = 0; cc < 4; ++cc) {
        const int n = n0 + cc*16 + x;
        const float bias = bc[n];
        #pragma unroll
        for (int r = 0; r < 4; ++r) {
            const int m = m0 + g*4 + r;
            float val = acc[cc][r] + bias;
            short hh = f2bf(val);
            Phi[(size_t)m*512 + n] = hh;
            Plo[(size_t)m*512 + n] = f2bf(val - bf2f(hh));
        }
    }
}

// ---------------------------------------------------------------------------
// Kernel 4: fused attention, all-MFMA.
// Block = 4 waves = 16 q-rows x 1024 k; wave w owns k in [256w, 256w+256).
// Scores: 3-pass split-bf16 MFMA; softmax: shfl + LDS cross-wave reduce;
// attn matrix written from C-frags; p staged bf16 in XOR-swizzled LDS;
// PV: 32 MFMAs, A from swizzled ds_read_b128, B from vT (bf16 single-pass).
// ---------------------------------------------------------------------------
__global__ __launch_bounds__(256)
void attn_kernel(const short* __restrict__ Phi, const short* __restrict__ Plo,
                 const short* __restrict__ vT, const unsigned char* __restrict__ mask,
                 float* __restrict__ out)
{
    __shared__ short pbuf[16*1024];       // [row][k] bf16, byte ^= (row&7)<<4
    __shared__ float redmax[4][4][4];     // [wave][g][r]
    __shared__ float redsum[4][4][4];

    const int q0 = blockIdx.x * 16;
    const int b  = blockIdx.y;
    const int h  = blockIdx.z;
    const int t  = threadIdx.x;
    const int lane = t & 63, w = t >> 6;
    const int x = lane & 15, g = lane >> 4;
    const int kbase = w * 256;

    // Q fragments (A): lane -> q-row q0+x, d-slice g*8..g*8+8
    const size_t qoff = ((size_t)(b*TT) + q0 + x)*512 + h*DK + g*8;
    const bf16x8 qhi = *(const bf16x8*)(Phi + qoff);
    const bf16x8 qlo = *(const bf16x8*)(Plo + qoff);

    // ---- scores: 16 chunks of 16 k, 3 MFMAs each ----
    f32x4 acc[16];
    #pragma unroll
    for (int c = 0; c < 16; ++c) {
        const int k0 = kbase + c*16;
        const size_t koff = ((size_t)(b*TT) + k0 + x)*512 + 256 + h*DK + g*8;
        bf16x8 khi = *(const bf16x8*)(Phi + koff);
        bf16x8 klo = *(const bf16x8*)(Plo + koff);
        f32x4 a; a[0] = 0.f; a[1] = 0.f; a[2] = 0.f; a[3] = 0.f;
        a = __builtin_amdgcn_mfma_f32_16x16x32_bf16(qhi, khi, a, 0, 0, 0);
        a = __builtin_amdgcn_mfma_f32_16x16x32_bf16(qlo, khi, a, 0, 0, 0);
        a = __builtin_amdgcn_mfma_f32_16x16x32_bf16(qhi, klo, a, 0, 0, 0);
        const unsigned char mk = mask[(size_t)b*TT + k0 + x];
        if (mk) { a[0] = -1000.f; a[1] = -1000.f; a[2] = -1000.f; a[3] = -1000.f; }
        acc[c] = a;
    }

    // ---- softmax (rows = q0 + g*4 + r; cols live in x-lanes & chunks & waves)
    float M[4], S[4];
    #pragma unroll
    for (int r = 0; r < 4; ++r) {
        float m = acc[0][r];
        #pragma unroll
        for (int c = 1; c < 16; ++c) m = fmaxf(m, acc[c][r]);
        m = fmaxf(m, __shfl_xor(m, 1, 64));
        m = fmaxf(m, __shfl_xor(m, 2, 64));
        m = fmaxf(m, __shfl_xor(m, 4, 64));
        m = fmaxf(m, __shfl_xor(m, 8, 64));
        M[r] = m;
    }
    if (x == 0) {
        redmax[w][g][0] = M[0]; redmax[w][g][1] = M[1];
        redmax[w][g][2] = M[2]; redmax[w][g][3] = M[3];
    }
    __syncthreads();
    #pragma unroll
    for (int r = 0; r < 4; ++r) {
        float m = fmaxf(fmaxf(redmax[0][g][r], redmax[1][g][r]),
                        fmaxf(redmax[2][g][r], redmax[3][g][r]));
        float s = 0.f;
        #pragma unroll
        for (int c = 0; c < 16; ++c) {
            float e = __expf(acc[c][r] - m);
            acc[c][r] = e;
            s += e;
        }
        s += __shfl_xor(s, 1, 64);
        s += __shfl_xor(s, 2, 64);
        s += __shfl_xor(s, 4, 64);
        s += __shfl_xor(s, 8, 64);
        S[r] = s;
    }
    if (x == 0) {
        redsum[w][g][0] = S[0]; redsum[w][g][1] = S[1];
        redsum[w][g][2] = S[2]; redsum[w][g][3] = S[3];
    }
    __syncthreads();
    float inv[4];
    #pragma unroll
    for (int r = 0; r < 4; ++r)
        inv[r] = 1.f / (redsum[0][g][r] + redsum[1][g][r] +
                        redsum[2][g][r] + redsum[3][g][r]);

    // ---- write attn matrix + stage p (bf16, swizzled) ----
    float* abase = out + OUT_OFF + ((size_t)(h*BB + b)*TT + q0)*TT;
    #pragma unroll
    for (int r = 0; r < 4; ++r) {
        const int row = g*4 + r;
        float* rp = abase + (size_t)row*TT + kbase + x;
        const int sw = (row & 7) << 4;
        #pragma unroll
        for (int c = 0; c < 16; ++c) {
            float p = acc[c][r] * inv[r];
            rp[c*16] = p;
            const int col = kbase + c*16 + x;
            pbuf[(row << 10) + ((((col << 1) ^ sw)) >> 1)] = f2bf(p);
        }
    }
    __syncthreads();

    // ---- PV: O[q][dh] = sum_t p[q][t] * v[t][dh]; wave w -> dh chunk w ----
    f32x4 o; o[0] = 0.f; o[1] = 0.f; o[2] = 0.f; o[3] = 0.f;
    const short* vrow = vT + ((size_t)(b*NHEAD + h)*DH + w*16 + x)*TT;
    const char* pbb = (const char*)pbuf;
    const int xsw = (x & 7) << 4;
    #pragma unroll
    for (int kk = 0; kk < 32; ++kk) {
        const int off = (x << 11) + ((kk*64 + g*16) ^ xsw);   // byte offset
        bf16x8 pa = *(const bf16x8*)(pbb + off);
        bf16x8 vb = *(const bf16x8*)(vrow + kk*32 + g*8);
        o = __builtin_amdgcn_mfma_f32_16x16x32_bf16(pa, vb, o, 0, 0, 0);
    }
    #pragma unroll
    for (int r = 0; r < 4; ++r)
        out[((size_t)(h*BB + b)*TT + q0 + g*4 + r)*DH + w*16 + x] = o[r];
}

// ---------------------------------------------------------------------------
extern "C" void kernel_launch(void* const* d_in, const int* in_sizes, int n_in,
                              void* d_out, int out_size, void* d_ws, size_t ws_size,
                              hipStream_t stream)
{
    // setup_inputs order: q, k, v, pad_mask, W_q, b_q, W_k, b_k
    const float* v  = (const float*)d_in[2];
    const unsigned char* mask_raw = (const unsigned char*)d_in[3];
    const float* Wq = (const float*)d_in[4];
    const float* bq = (const float*)d_in[5];
    const float* Wk = (const float*)d_in[6];
    const float* bk = (const float*)d_in[7];
    float* out = (float*)d_out;

    char* ws = (char*)d_ws;
    short* Phi = (short*)ws;  ws += (size_t)BB*TT*512*2;   // 16.8 MB  qh|kh hi
    short* Plo = (short*)ws;  ws += (size_t)BB*TT*512*2;   // 16.8 MB  qh|kh lo
    short* vT  = (short*)ws;  ws += (size_t)BB*NHEAD*DH*TT*2; // 16.8 MB
    short* Whi = (short*)ws;  ws += (size_t)512*512*2;     // 0.5 MB
    short* Wlo = (short*)ws;  ws += (size_t)512*512*2;     // 0.5 MB
    float* bc  = (float*)ws;  ws += 512*4;
    unsigned char* mask_norm = (unsigned char*)ws;         // 16 KB

    mask_repack_kernel<<<1, 256, 0, stream>>>(mask_raw, mask_norm);
    conv_w_kernel<<<512, 256, 0, stream>>>(Wq, bq, Wk, bk, Whi, Wlo, bc);
    conv_vt_kernel<<<dim3(TT/64, BB, NHEAD), 256, 0, stream>>>(v, vT);
    proj_kernel<<<dim3(256, 8), 256, 0, stream>>>(v, Whi, Wlo, bc, Phi, Plo);
    attn_kernel<<<dim3(TT/16, BB, NHEAD), 256, 0, stream>>>(Phi, Plo, vT, mask_norm, out);
}